// Round 6
// baseline (104.352 us; speedup 1.0000x reference)
//
#include <hip/hip_runtime.h>
#include <hip/hip_bf16.h>

// SwitchLinear: out[b,o] = sum_i x[b,i]*W[o,i,c_b] + bias[o,c_b]
// x,W,bias,out = fp32; idx = int32. B=8192 I=O=256 C=32.
// ONE plain dispatch (512 blocks): producer blocks transpose W->bf16 / bucket
// channels, publish via device-scope flags (release: threadfence+atomicExch);
// all blocks poll flags with device-scope atomic reads, acquire-fence, then
// run the grouped MFMA GEMM (fp32 x converted to bf16 inline at staging).
// Deadlock-safe: 512 blocks always co-resident (LDS 35.1KB -> >=2 blocks/CU).
#define NB 8192
#define NI 256
#define NO 256
#define NC 32

#define POISON 0xAAAAAAAAu
#define NFLAGS 288                 // 256 transpose producers + 32 bucket producers

typedef __attribute__((ext_vector_type(8))) short short8;   // 8 x bf16
typedef __attribute__((ext_vector_type(4))) float floatx4;  // MFMA acc

// ---- workspace layout (bytes) ----
#define WS_FLAGS_OFF  0            // uint flags[288]; bucket flag = count+1
#define WS_LISTS_OFF  (4u << 10)   // ushort lists[NC][NB]  (512 KB)
#define WS_WT_OFF     (1u << 20)   // ushort wT[NC][NO][NI] (4 MB)

static __device__ __forceinline__ unsigned short f2bf(float f) {
    __hip_bfloat16 h = __float2bfloat16(f);   // RNE
    return *(unsigned short*)&h;
}

__global__ __launch_bounds__(256) void k_fused(
        const int* __restrict__ idx,
        const float* __restrict__ x,
        const float* __restrict__ w,
        const float* __restrict__ bias,
        unsigned int* flags,
        unsigned short* __restrict__ lists,
        unsigned short* __restrict__ wT,
        float* __restrict__ out) {
    __shared__ unsigned short As[64][136];   // rows padded: 272 B, 16B-aligned
    __shared__ unsigned short Bs[64][136];   // 68 dw == 4 mod 32 -> 2-way free
    __shared__ int blist[64];
    __shared__ unsigned int lcnt;

    const int bid = blockIdx.x;
    const int tid = threadIdx.x;

    // ================= phase 1: producers =================
    if (bid < 256) {
        // transpose W[o][i][c] fp32 -> wT[c][o][i] bf16 ; block bid owns o=bid
        int g = bid * 256 + tid;   // g = o*NI + i
        const float4* src = (const float4*)(w + (size_t)g * NC);
        unsigned short vals[NC];
#pragma unroll
        for (int s = 0; s < 8; ++s) {
            float4 v = src[s];
            vals[s * 4 + 0] = f2bf(v.x);
            vals[s * 4 + 1] = f2bf(v.y);
            vals[s * 4 + 2] = f2bf(v.z);
            vals[s * 4 + 3] = f2bf(v.w);
        }
#pragma unroll
        for (int c = 0; c < NC; ++c) {
            // fixed c: 64 consecutive g per wave -> 128 B contiguous store
            wT[(size_t)c * (NO * NI) + g] = vals[c];
        }
        __syncthreads();             // all waves' stores drained (vmcnt) at barrier
        if (tid == 0) {
            __threadfence();         // agent release: writeback L2 to coherence point
            atomicExch(&flags[bid], 1u);
        }
    } else if (bid < 288) {
        // bucket channel c = bid-256
        const int c = bid - 256;
        if (tid == 0) lcnt = 0u;
        __syncthreads();
        const int4* idx4 = (const int4*)idx;
        for (int t = tid; t < NB / 4; t += 256) {
            int4 v = idx4[t];
            int b0 = t * 4;
            if (v.x == c) lists[c * NB + atomicAdd(&lcnt, 1u)] = (unsigned short)(b0 + 0);
            if (v.y == c) lists[c * NB + atomicAdd(&lcnt, 1u)] = (unsigned short)(b0 + 1);
            if (v.z == c) lists[c * NB + atomicAdd(&lcnt, 1u)] = (unsigned short)(b0 + 2);
            if (v.w == c) lists[c * NB + atomicAdd(&lcnt, 1u)] = (unsigned short)(b0 + 3);
        }
        __syncthreads();
        if (tid == 0) {
            __threadfence();
            atomicExch(&flags[bid], lcnt + 1u);   // never 0, never POISON
        }
    }

    // ================= soft barrier: poll producer flags =================
    if (tid < 64) {
        bool done = false;
        while (!done) {
            unsigned int miss = 0u;
#pragma unroll
            for (int f = tid; f < NFLAGS; f += 64) {
                unsigned int v = atomicAdd(&flags[f], 0u);  // device-scope read
                miss |= (unsigned int)(v == POISON || v == 0u);
            }
            done = (__ballot(miss != 0u) == 0ull);
            if (!done) __builtin_amdgcn_s_sleep(2);
        }
        if (tid == 0) __threadfence();   // agent acquire: invalidate stale L1/L2
    }
    __syncthreads();

    // ================= phase 2: grouped GEMM =================
    // bid -> (c, o-tile, z in [0,4)); persistent over m-tiles (mt += 4).
    const int c    = bid & 31;
    const int rest = bid >> 5;           // 0..15
    const int o0   = (rest & 3) * 64;
    const int z    = rest >> 2;          // 0..3
    const int cnt  = (int)(flags[256 + c] - 1u);

    const int wv    = tid >> 6;
    const int lane  = tid & 63;
    const int lrc   = lane & 15;         // A row m / B,D col n
    const int koff  = (lane >> 4) * 8;   // k offset within 32-chunk
    const int rbase = (lane >> 4) * 4;

    const unsigned short* wTc = wT + ((size_t)c * NO + o0) * NI;
    const int o = o0 + wv * 16 + lrc;
    const float bv = bias[o * NC + c];

    for (int mt = z; mt * 64 < cnt; mt += 4) {
        const int m0 = mt * 64;
        if (tid < 64) {
            int mr = m0 + tid;
            blist[tid] = (int)lists[c * NB + (mr < cnt ? mr : m0)];
        }
        __syncthreads();

        floatx4 acc[4];
#pragma unroll
        for (int ms = 0; ms < 4; ++ms) acc[ms] = (floatx4){0.f, 0.f, 0.f, 0.f};

#pragma unroll
        for (int kt = 0; kt < 2; ++kt) {
            const int kb = kt * 128;
#pragma unroll
            for (int s = 0; s < 4; ++s) {
                int lin = tid + s * 256;   // 64 rows x 8 segs of 8 elems
                int row = lin >> 4;
                int c8  = (lin & 15) * 8;
                // A: fp32 -> bf16 inline
                const float4* pa = (const float4*)(x + (size_t)blist[row] * NI + kb + c8);
                float4 a0 = pa[0], a1 = pa[1];
                unsigned short r[8];
                r[0] = f2bf(a0.x); r[1] = f2bf(a0.y); r[2] = f2bf(a0.z); r[3] = f2bf(a0.w);
                r[4] = f2bf(a1.x); r[5] = f2bf(a1.y); r[6] = f2bf(a1.z); r[7] = f2bf(a1.w);
                *(uint4*)&As[row][c8] = *(uint4*)r;
                // B: bf16 straight copy
                *(uint4*)&Bs[row][c8] = *(const uint4*)(wTc + (size_t)row * NI + kb + c8);
            }
            __syncthreads();

            const int n0 = wv * 16;
#pragma unroll
            for (int k0 = 0; k0 < 4; ++k0) {
                short8 bfrag = *(const short8*)&Bs[n0 + lrc][k0 * 32 + koff];
#pragma unroll
                for (int ms = 0; ms < 4; ++ms) {
                    short8 afrag = *(const short8*)&As[ms * 16 + lrc][k0 * 32 + koff];
                    acc[ms] = __builtin_amdgcn_mfma_f32_16x16x32_bf16(afrag, bfrag, acc[ms], 0, 0, 0);
                }
            }
            __syncthreads();
        }

        // D layout: col = lane&15, row = (lane>>4)*4 + reg
#pragma unroll
        for (int ms = 0; ms < 4; ++ms) {
#pragma unroll
            for (int r = 0; r < 4; ++r) {
                int row = ms * 16 + rbase + r;
                if (m0 + row < cnt) {
                    out[(size_t)blist[row] * NO + o] = acc[ms][r] + bv;
                }
            }
        }
        __syncthreads();   // protect blist/As/Bs for next persistent iteration
    }
}

extern "C" void kernel_launch(void* const* d_in, const int* in_sizes, int n_in,
                              void* d_out, int out_size, void* d_ws, size_t ws_size,
                              hipStream_t stream) {
    const float* x    = (const float*)d_in[0];   // fp32 [NB][NI]
    const int*   idx  = (const int*)d_in[1];     // int32 [NB]
    const float* w    = (const float*)d_in[2];   // fp32 [NO][NI][NC]
    const float* bias = (const float*)d_in[3];   // fp32 [NO][NC]
    float* out = (float*)d_out;                  // fp32 [NB][NO]

    char* ws = (char*)d_ws;
    unsigned int*   flags = (unsigned int*)(ws + WS_FLAGS_OFF);
    unsigned short* lists = (unsigned short*)(ws + WS_LISTS_OFF);
    unsigned short* wT    = (unsigned short*)(ws + WS_WT_OFF);

    k_fused<<<512, 256, 0, stream>>>(idx, x, w, bias, flags, lists, wT, out);
}

// Round 7
// 101.009 us; speedup vs baseline: 1.0331x; 1.0331x over previous
//
#include <hip/hip_runtime.h>
#include <hip/hip_bf16.h>

// SwitchLinear: out[b,o] = sum_i x[b,i]*W[o,i,c_b] + bias[o,c_b]
// x,W,bias,out = fp32; idx = int32. B=8192 I=O=256 C=32.
// 2 dispatches:
//   k_prep: W[o][i][c] fp32 -> wT[c][o][i] bf16 (256 blocks) + channel bucket (32 blocks)
//   k_gemm: grouped MFMA GEMM, BARRIER-FREE & LDS-FREE:
//     - B-frags hoisted to registers once per block (invariant over m-tiles)
//     - A-frags built from global fp32 x with inline RNE bf16 cvt
//     (R6's single-dispatch flag handshake regressed +21us: device-scope fences
//      + flag-poll RMWs cost more than a dispatch boundary. Reverted.)
#define NB 8192
#define NI 256
#define NO 256
#define NC 32

typedef __attribute__((ext_vector_type(8))) short short8;   // 8 x bf16
typedef __attribute__((ext_vector_type(4))) float floatx4;  // MFMA acc

// ---- workspace layout (bytes) ----
#define WS_COUNTS_OFF 0            // uint counts[NC]
#define WS_LISTS_OFF  (4u << 10)   // ushort lists[NC][NB]  (512 KB)
#define WS_WT_OFF     (1u << 20)   // ushort wT[NC][NO][NI] (4 MB)

static __device__ __forceinline__ unsigned short f2bf(float f) {
    __hip_bfloat16 h = __float2bfloat16(f);   // RNE
    return *(unsigned short*)&h;
}

// prep: blocks [0,256) transpose W -> wT bf16; blocks [256,288) bucket channels.
#define PREP_BLOCKS 288

__global__ __launch_bounds__(256) void k_prep(
        const int* __restrict__ idx,
        const float* __restrict__ w,
        unsigned int* __restrict__ counts,
        unsigned short* __restrict__ lists,
        unsigned short* __restrict__ wT) {
    const int bid = blockIdx.x;
    const int tid = threadIdx.x;

    if (bid < 256) {
        int g = bid * 256 + tid;   // g = o*NI + i, 0..65535
        const float4* src = (const float4*)(w + (size_t)g * NC);
        unsigned short vals[NC];
#pragma unroll
        for (int s = 0; s < 8; ++s) {
            float4 v = src[s];
            vals[s * 4 + 0] = f2bf(v.x);
            vals[s * 4 + 1] = f2bf(v.y);
            vals[s * 4 + 2] = f2bf(v.z);
            vals[s * 4 + 3] = f2bf(v.w);
        }
#pragma unroll
        for (int c = 0; c < NC; ++c) {
            // fixed c: 64 consecutive g per wave -> 128 B contiguous store
            wT[(size_t)c * (NO * NI) + g] = vals[c];
        }
    } else {
        __shared__ unsigned int lcnt;
        const int c = bid - 256;
        if (tid == 0) lcnt = 0u;
        __syncthreads();
        const int4* idx4 = (const int4*)idx;
        for (int t = tid; t < NB / 4; t += 256) {
            int4 v = idx4[t];
            int b0 = t * 4;
            if (v.x == c) lists[c * NB + atomicAdd(&lcnt, 1u)] = (unsigned short)(b0 + 0);
            if (v.y == c) lists[c * NB + atomicAdd(&lcnt, 1u)] = (unsigned short)(b0 + 1);
            if (v.z == c) lists[c * NB + atomicAdd(&lcnt, 1u)] = (unsigned short)(b0 + 2);
            if (v.w == c) lists[c * NB + atomicAdd(&lcnt, 1u)] = (unsigned short)(b0 + 3);
        }
        __syncthreads();
        if (tid == 0) counts[c] = lcnt;
    }
}

// Grouped GEMM: grid (c, o-tile, z=8), block = 256 = 4 waves, persistent in m.
// Tile M=64 x N=64, K=256. No LDS, no __syncthreads: B in registers (8 frags),
// A streamed from global fp32 with inline cvt. MFMA 16x16x32 bf16.
// A layout: elem j = A[m=lane&15][k = kc*32 + (lane>>4)*8 + j]
// B layout: elem j = B[k = kc*32 + (lane>>4)*8 + j][n=lane&15] (wT row-major in o)
// D layout: col = lane&15, row = (lane>>4)*4 + reg
__global__ __launch_bounds__(256, 4) void k_gemm(
        const float* __restrict__ x,
        const unsigned short* __restrict__ wT,
        const float* __restrict__ bias,
        const unsigned int* __restrict__ counts,
        const unsigned short* __restrict__ lists,
        float* __restrict__ out) {
    const int c   = blockIdx.x;
    const int o0  = blockIdx.y * 64;
    const int cnt = (int)counts[c];
    if ((int)blockIdx.z * 64 >= cnt) return;   // uniform dead-block exit

    const int tid  = threadIdx.x;
    const int wv   = tid >> 6;
    const int lane = tid & 63;
    const int lrc  = lane & 15;          // A row m / B,D col n
    const int kg   = lane >> 4;          // quad group 0..3
    const int koff = kg * 8;             // k offset within 32-chunk
    const int rbase = kg * 4;

    // ---- hoist B: 8 frags, invariant over the m-loop ----
    const unsigned short* bp =
        wT + ((size_t)c * NO + o0 + wv * 16 + lrc) * NI + koff;
    short8 bq[8];
#pragma unroll
    for (int kc = 0; kc < 8; ++kc) bq[kc] = *(const short8*)(bp + kc * 32);

    const int o = o0 + wv * 16 + lrc;
    const float bv = bias[o * NC + c];
    const unsigned short* lc = lists + c * NB;

    for (int mt = blockIdx.z; mt * 64 < cnt; mt += 8) {
        const int m0 = mt * 64;

        // per-lane A row pointers (rows clamped; OOB rows skipped at store)
        const float* rp[4];
#pragma unroll
        for (int ms = 0; ms < 4; ++ms) {
            int mr = m0 + ms * 16 + lrc;
            rp[ms] = x + (size_t)lc[mr < cnt ? mr : m0] * NI + koff;
        }

        floatx4 acc[4];
#pragma unroll
        for (int ms = 0; ms < 4; ++ms) acc[ms] = (floatx4){0.f, 0.f, 0.f, 0.f};

#pragma unroll
        for (int kc = 0; kc < 8; ++kc) {
#pragma unroll
            for (int ms = 0; ms < 4; ++ms) {
                float4 a0 = *(const float4*)(rp[ms] + kc * 32);
                float4 a1 = *(const float4*)(rp[ms] + kc * 32 + 4);
                unsigned short r[8];
                r[0] = f2bf(a0.x); r[1] = f2bf(a0.y); r[2] = f2bf(a0.z); r[3] = f2bf(a0.w);
                r[4] = f2bf(a1.x); r[5] = f2bf(a1.y); r[6] = f2bf(a1.z); r[7] = f2bf(a1.w);
                acc[ms] = __builtin_amdgcn_mfma_f32_16x16x32_bf16(
                    *(const short8*)r, bq[kc], acc[ms], 0, 0, 0);
            }
        }

        // epilogue: D col = lrc, row = rbase + reg (+16*ms)
#pragma unroll
        for (int ms = 0; ms < 4; ++ms) {
#pragma unroll
            for (int r = 0; r < 4; ++r) {
                int row = ms * 16 + rbase + r;
                if (m0 + row < cnt) {
                    out[(size_t)lc[m0 + row] * NO + o] = acc[ms][r] + bv;
                }
            }
        }
    }
}

extern "C" void kernel_launch(void* const* d_in, const int* in_sizes, int n_in,
                              void* d_out, int out_size, void* d_ws, size_t ws_size,
                              hipStream_t stream) {
    const float* x    = (const float*)d_in[0];   // fp32 [NB][NI]
    const int*   idx  = (const int*)d_in[1];     // int32 [NB]
    const float* w    = (const float*)d_in[2];   // fp32 [NO][NI][NC]
    const float* bias = (const float*)d_in[3];   // fp32 [NO][NC]
    float* out = (float*)d_out;                  // fp32 [NB][NO]

    char* ws = (char*)d_ws;
    unsigned int*   counts = (unsigned int*)(ws + WS_COUNTS_OFF);
    unsigned short* lists  = (unsigned short*)(ws + WS_LISTS_OFF);
    unsigned short* wT     = (unsigned short*)(ws + WS_WT_OFF);

    k_prep<<<PREP_BLOCKS, 256, 0, stream>>>(idx, w, counts, lists, wT);
    dim3 grid(NC, NO / 64, 8);
    k_gemm<<<grid, 256, 0, stream>>>(x, wT, bias, counts, lists, out);
}

// Round 8
// 82.872 us; speedup vs baseline: 1.2592x; 1.2189x over previous
//
#include <hip/hip_runtime.h>
#include <hip/hip_bf16.h>

// SwitchLinear: out[b,o] = sum_i x[b,i]*W[o,i,c_b] + bias[o,c_b]
// x,W,bias,out = fp32; idx = int32. B=8192 I=O=256 C=32.
// Proven R5 skeleton (2 dispatches) + micro-opts:
//   - GEMM z=4 (was 8): fewer dead blocks, persistent mt loop handles any cnt
//   - transpose: 2 g/thread -> ushort2 stores (2x store width), 128+32 blocks
// History: R4 cooperative launch rejected at validation; R6 flag-handshake
// single-dispatch +21us (device fences + atomic polling >> dispatch boundary);
// R7 LDS-free per-lane A gather +18us (uncoalesced, 4x redundant). Keep LDS tile.
#define NB 8192
#define NI 256
#define NO 256
#define NC 32

typedef __attribute__((ext_vector_type(8))) short short8;   // 8 x bf16
typedef __attribute__((ext_vector_type(4))) float floatx4;  // MFMA acc

// ---- workspace layout (bytes) ----
#define WS_COUNTS_OFF 0            // uint counts[NC]
#define WS_LISTS_OFF  (4u << 10)   // ushort lists[NC][NB]  (512 KB)
#define WS_WT_OFF     (1u << 20)   // ushort wT[NC][NO][NI] (4 MB)

static __device__ __forceinline__ unsigned short f2bf(float f) {
    __hip_bfloat16 h = __float2bfloat16(f);   // RNE
    return *(unsigned short*)&h;
}

// prep: blocks [0,128) transpose W -> wT bf16 (512 g each, 2 g/thread);
//       blocks [128,160) bucket channel c = bid-128 (LDS counter).
#define PREP_TRAN 128
#define PREP_BLOCKS (PREP_TRAN + NC)

__global__ __launch_bounds__(256) void k_prep(
        const int* __restrict__ idx,
        const float* __restrict__ w,
        unsigned int* __restrict__ counts,
        unsigned short* __restrict__ lists,
        unsigned short* __restrict__ wT) {
    const int bid = blockIdx.x;
    const int tid = threadIdx.x;

    if (bid < PREP_TRAN) {
        // thread handles g0 = 2*(bid*256+tid) and g0+1  (g = o*NI + i)
        int g0 = (bid * 256 + tid) * 2;
        const float4* s0 = (const float4*)(w + (size_t)g0 * NC);
        unsigned short v0[NC], v1[NC];
#pragma unroll
        for (int s = 0; s < 8; ++s) {
            float4 a = s0[s];
            v0[s * 4 + 0] = f2bf(a.x); v0[s * 4 + 1] = f2bf(a.y);
            v0[s * 4 + 2] = f2bf(a.z); v0[s * 4 + 3] = f2bf(a.w);
        }
#pragma unroll
        for (int s = 0; s < 8; ++s) {
            float4 a = s0[8 + s];
            v1[s * 4 + 0] = f2bf(a.x); v1[s * 4 + 1] = f2bf(a.y);
            v1[s * 4 + 2] = f2bf(a.z); v1[s * 4 + 3] = f2bf(a.w);
        }
#pragma unroll
        for (int c = 0; c < NC; ++c) {
            // fixed c: 64 lanes x 4 B = 256 B contiguous store per wave-instr
            unsigned short pair[2] = {v0[c], v1[c]};
            *(unsigned int*)(wT + (size_t)c * (NO * NI) + g0) = *(unsigned int*)pair;
        }
    } else {
        __shared__ unsigned int lcnt;
        const int c = bid - PREP_TRAN;
        if (tid == 0) lcnt = 0u;
        __syncthreads();
        const int4* idx4 = (const int4*)idx;
        for (int t = tid; t < NB / 4; t += 256) {
            int4 v = idx4[t];
            int b0 = t * 4;
            if (v.x == c) lists[c * NB + atomicAdd(&lcnt, 1u)] = (unsigned short)(b0 + 0);
            if (v.y == c) lists[c * NB + atomicAdd(&lcnt, 1u)] = (unsigned short)(b0 + 1);
            if (v.z == c) lists[c * NB + atomicAdd(&lcnt, 1u)] = (unsigned short)(b0 + 2);
            if (v.w == c) lists[c * NB + atomicAdd(&lcnt, 1u)] = (unsigned short)(b0 + 3);
        }
        __syncthreads();
        if (tid == 0) counts[c] = lcnt;
    }
}

// Grouped GEMM: grid (c, o-tile, z=4), block = 256 = 4 waves, persistent in m.
// Tile M=64 (gathered rows), N=64 outputs, K streamed 2 x 128 (bf16 LDS).
// A-tile: fp32 global loads (2 x float4/lane) converted to bf16 in-register.
// LDS rows padded to 136 bf16 (272 B, 16B-aligned; 68 dw == 4 mod 32 -> 2-way free).
__launch_bounds__(256)
__global__ void k_gemm(const float* __restrict__ x,
                       const unsigned short* __restrict__ wT,
                       const float* __restrict__ bias,
                       const unsigned int* __restrict__ counts,
                       const unsigned short* __restrict__ lists,
                       float* __restrict__ out) {
    const int c  = blockIdx.x;
    const int o0 = blockIdx.y * 64;
    const int cnt = (int)counts[c];

    __shared__ unsigned short As[64][136];
    __shared__ unsigned short Bs[64][136];
    __shared__ int blist[64];

    const int tid  = threadIdx.x;
    const int wv   = tid >> 6;
    const int lane = tid & 63;
    const int lrc  = lane & 15;        // A row m / B,D col n
    const int koff = (lane >> 4) * 8;  // k offset within 32-chunk
    const int rbase = (lane >> 4) * 4;

    const unsigned short* wTc = wT + ((size_t)c * NO + o0) * NI;
    const int o = o0 + wv * 16 + lrc;
    const float bv = bias[o * NC + c];

    for (int mt = blockIdx.z; mt * 64 < cnt; mt += 4) {
        const int m0 = mt * 64;
        if (tid < 64) {
            int mr = m0 + tid;
            blist[tid] = (int)lists[c * NB + (mr < cnt ? mr : m0)];
        }
        __syncthreads();

        floatx4 acc[4];
#pragma unroll
        for (int ms = 0; ms < 4; ++ms) acc[ms] = (floatx4){0.f, 0.f, 0.f, 0.f};

#pragma unroll
        for (int kt = 0; kt < 2; ++kt) {
            const int kb = kt * 128;
#pragma unroll
            for (int s = 0; s < 4; ++s) {
                int lin = tid + s * 256;   // 64 rows x 8 segs of 8 elems
                int row = lin >> 4;
                int c8  = (lin & 15) * 8;
                // A: fp32 -> bf16 inline
                const float4* pa = (const float4*)(x + (size_t)blist[row] * NI + kb + c8);
                float4 a0 = pa[0], a1 = pa[1];
                unsigned short r[8];
                r[0] = f2bf(a0.x); r[1] = f2bf(a0.y); r[2] = f2bf(a0.z); r[3] = f2bf(a0.w);
                r[4] = f2bf(a1.x); r[5] = f2bf(a1.y); r[6] = f2bf(a1.z); r[7] = f2bf(a1.w);
                *(uint4*)&As[row][c8] = *(uint4*)r;
                // B: bf16 straight copy
                *(uint4*)&Bs[row][c8] = *(const uint4*)(wTc + (size_t)row * NI + kb + c8);
            }
            __syncthreads();

            const int n0 = wv * 16;
#pragma unroll
            for (int k0 = 0; k0 < 4; ++k0) {
                short8 bfrag = *(const short8*)&Bs[n0 + lrc][k0 * 32 + koff];
#pragma unroll
                for (int ms = 0; ms < 4; ++ms) {
                    short8 afrag = *(const short8*)&As[ms * 16 + lrc][k0 * 32 + koff];
                    acc[ms] = __builtin_amdgcn_mfma_f32_16x16x32_bf16(afrag, bfrag, acc[ms], 0, 0, 0);
                }
            }
            __syncthreads();
        }

        // D layout: col = lane&15, row = (lane>>4)*4 + reg
#pragma unroll
        for (int ms = 0; ms < 4; ++ms) {
#pragma unroll
            for (int r = 0; r < 4; ++r) {
                int row = ms * 16 + rbase + r;
                if (m0 + row < cnt) {
                    out[(size_t)blist[row] * NO + o] = acc[ms][r] + bv;
                }
            }
        }
        __syncthreads();   // protect blist/As/Bs for next persistent iteration
    }
}

extern "C" void kernel_launch(void* const* d_in, const int* in_sizes, int n_in,
                              void* d_out, int out_size, void* d_ws, size_t ws_size,
                              hipStream_t stream) {
    const float* x    = (const float*)d_in[0];   // fp32 [NB][NI]
    const int*   idx  = (const int*)d_in[1];     // int32 [NB]
    const float* w    = (const float*)d_in[2];   // fp32 [NO][NI][NC]
    const float* bias = (const float*)d_in[3];   // fp32 [NO][NC]
    float* out = (float*)d_out;                  // fp32 [NB][NO]

    char* ws = (char*)d_ws;
    unsigned int*   counts = (unsigned int*)(ws + WS_COUNTS_OFF);
    unsigned short* lists  = (unsigned short*)(ws + WS_LISTS_OFF);
    unsigned short* wT     = (unsigned short*)(ws + WS_WT_OFF);

    k_prep<<<PREP_BLOCKS, 256, 0, stream>>>(idx, w, counts, lists, wT);
    dim3 grid(NC, NO / 64, 4);
    k_gemm<<<grid, 256, 0, stream>>>(x, wT, bias, counts, lists, out);
}